// Round 10
// baseline (1090.757 us; speedup 1.0000x reference)
//
#include <hip/hip_runtime.h>

#define NN 100000
#define NE 3200000
#define NG 256
#define F0 128
#define F1 64
#define F2 64
#define F3 32
#define NPAD 100352   // 1568 * 64, > NN+1
#define WD 80         // ELL row width; deg ~ Poisson(32), P(deg>=80) ~ 1e-13/node
#define NBINS 1568    // NPAD >> 6
#define BSH 6         // 64 nodes per bin

// ---------------- Phase A: per-bin histogram (LDS-staged) ----------------
__global__ __launch_bounds__(256) void k_hist(const int* __restrict__ dst,
                                              int* __restrict__ bhist, int e) {
    __shared__ int lh[NBINS];
    for (int i = threadIdx.x; i < NBINS; i += 256) lh[i] = 0;
    __syncthreads();
    for (int i = blockIdx.x * 256 + threadIdx.x; i < e; i += gridDim.x * 256)
        atomicAdd(&lh[dst[i] >> BSH], 1);
    __syncthreads();
    for (int i = threadIdx.x; i < NBINS; i += 256) {
        int v = lh[i];
        if (v) atomicAdd(&bhist[i], v);
    }
}

// ---------------- scan of 1568 bin counts (one block) ----------------
__global__ __launch_bounds__(1024) void k_scan(const int* __restrict__ bhist,
                                               int* __restrict__ binoff,
                                               int* __restrict__ cursor) {
    __shared__ int s[1024];
    __shared__ int carry;
    if (threadIdx.x == 0) carry = 0;
    __syncthreads();
    for (int c = 0; c < 2; ++c) {
        int idx = c * 1024 + threadIdx.x;
        int v = (idx < NBINS) ? bhist[idx] : 0;
        s[threadIdx.x] = v;
        __syncthreads();
        for (int off = 1; off < 1024; off <<= 1) {
            int t = (threadIdx.x >= off) ? s[threadIdx.x - off] : 0;
            __syncthreads();
            s[threadIdx.x] += t;
            __syncthreads();
        }
        int excl = s[threadIdx.x] - v + carry;
        if (idx < NBINS) { binoff[idx] = excl; cursor[idx] = excl; }
        __syncthreads();
        if (threadIdx.x == 1023) carry += s[1023];
        __syncthreads();
    }
    if (threadIdx.x == 0) binoff[NBINS] = carry;   // = e
}

// ---------------- Phase B: partition edges into bin-grouped pair list ----------------
__global__ void k_part(const int* __restrict__ src, const int* __restrict__ dst,
                       int* __restrict__ cursor, int2* __restrict__ pairs, int e) {
    int i = blockIdx.x * blockDim.x + threadIdx.x;
    if (i >= e) return;
    int s = src[i], d = dst[i];
    int pos = atomicAdd(&cursor[d >> BSH], 1);
    pairs[pos] = make_int2(s, d);
}

// ---------------- Phase C: per-bin ELL placement via LDS counters; fuses cnt+dinv ----------------
__global__ __launch_bounds__(256) void k_place(const int2* __restrict__ pairs,
                                               const int* __restrict__ binoff,
                                               int* __restrict__ ssrc,
                                               int* __restrict__ cnt,
                                               float* __restrict__ dinv) {
    __shared__ int lc[64];
    int b = blockIdx.x;
    if (threadIdx.x < 64) lc[threadIdx.x] = 0;
    __syncthreads();
    int beg = binoff[b], end = binoff[b + 1];
    for (int i = beg + threadIdx.x; i < end; i += 256) {
        int2 p = pairs[i];
        int pos = atomicAdd(&lc[p.y & 63], 1);
        if (pos < WD) ssrc[(size_t)p.y * WD + pos] = p.x;
    }
    __syncthreads();
    if (threadIdx.x < 64) {
        int node = (b << BSH) + threadIdx.x;
        int c = lc[threadIdx.x];
        cnt[node] = c;
        dinv[node] = rsqrtf((float)(c + 1));   // +1 self-loop
    }
}

// ---------------- GEMM: out[nn,:] = ((relu?)x[nn,:] @ W) * dinv[nn] ----------------
template<int F_IN, int F_OUT, bool RELU_IN>
__global__ __launch_bounds__(256) void k_gemm(const float* __restrict__ x,
                                              const float* __restrict__ W,
                                              const float* __restrict__ dinv,
                                              float* __restrict__ out, int n) {
    constexpr int NPB = 256 / F_OUT;   // nodes per block-tile
    __shared__ float Wl[F_IN * F_OUT];
    __shared__ float Xl[NPB * F_IN];
    const int tid = threadIdx.x;
    for (int i = tid; i < F_IN * F_OUT; i += 256) Wl[i] = W[i];

    const int nl = tid / F_OUT;
    const int f  = tid % F_OUT;
    const int ntiles = (n + NPB - 1) / NPB;

    for (int tile = blockIdx.x; tile < ntiles; tile += gridDim.x) {
        const int n0 = tile * NPB;
        __syncthreads();
        for (int i = tid; i < NPB * F_IN; i += 256) {
            int nn = n0 + i / F_IN;
            float v = (nn < n) ? x[(size_t)nn * F_IN + (i % F_IN)] : 0.f;
            Xl[i] = RELU_IN ? fmaxf(v, 0.f) : v;
        }
        __syncthreads();
        const int nn = n0 + nl;
        if (nn < n) {
            const int xb = nl * F_IN;
            float a0 = 0.f, a1 = 0.f, a2 = 0.f, a3 = 0.f;
#pragma unroll
            for (int k = 0; k < F_IN; k += 4) {
                a0 = fmaf(Xl[xb + k + 0], Wl[(k + 0) * F_OUT + f], a0);
                a1 = fmaf(Xl[xb + k + 1], Wl[(k + 1) * F_OUT + f], a1);
                a2 = fmaf(Xl[xb + k + 2], Wl[(k + 2) * F_OUT + f], a2);
                a3 = fmaf(Xl[xb + k + 3], Wl[(k + 3) * F_OUT + f], a3);
            }
            out[(size_t)nn * F_OUT + f] = ((a0 + a1) + (a2 + a3)) * dinv[nn];
        }
    }
}

// ---------------- ELL gather: out[d] = b + dinv[d] * (h'[d] + sum_{s in N(d)} h'[s]) ----------------
template<int F>
__global__ __launch_bounds__(256) void k_gather(const int* __restrict__ cnt,
                                                const int* __restrict__ ssrc,
                                                const float* __restrict__ dinv,
                                                const float* __restrict__ h,
                                                const float* __restrict__ b,
                                                float* __restrict__ out, int n) {
    constexpr int G = F / 4;
    int t = blockIdx.x * blockDim.x + threadIdx.x;
    int node = t / G;
    int g    = t % G;
    if (node >= n) return;
    float dd = dinv[node];
    float4 acc = ((const float4*)(h + (size_t)node * F))[g];   // self term h'[d]
    int c = cnt[node]; if (c > WD) c = WD;
    const int* row = ssrc + (size_t)node * WD;
    int j = 0;
    for (; j + 4 <= c; j += 4) {
        int4 s4 = *(const int4*)(row + j);
        float4 v0 = ((const float4*)(h + (size_t)s4.x * F))[g];
        float4 v1 = ((const float4*)(h + (size_t)s4.y * F))[g];
        float4 v2 = ((const float4*)(h + (size_t)s4.z * F))[g];
        float4 v3 = ((const float4*)(h + (size_t)s4.w * F))[g];
        acc.x += (v0.x + v1.x) + (v2.x + v3.x);
        acc.y += (v0.y + v1.y) + (v2.y + v3.y);
        acc.z += (v0.z + v1.z) + (v2.z + v3.z);
        acc.w += (v0.w + v1.w) + (v2.w + v3.w);
    }
    for (; j < c; ++j) {
        int s = row[j];
        float4 v = ((const float4*)(h + (size_t)s * F))[g];
        acc.x += v.x; acc.y += v.y; acc.z += v.z; acc.w += v.w;
    }
    float4 bb = ((const float4*)b)[g];
    float4 o;
    o.x = fmaf(dd, acc.x, bb.x);
    o.y = fmaf(dd, acc.y, bb.y);
    o.z = fmaf(dd, acc.z, bb.z);
    o.w = fmaf(dd, acc.w, bb.w);
    ((float4*)(out + (size_t)node * F))[g] = o;
}

// ---------------- pooled mean over sorted batch ----------------
__device__ __forceinline__ int lower_bound_i(const int* __restrict__ a, int n, int key) {
    int lo = 0, hi = n;
    while (lo < hi) { int mid = (lo + hi) >> 1; if (a[mid] < key) lo = mid + 1; else hi = mid; }
    return lo;
}

__global__ void k_pool(const float* __restrict__ h, const int* __restrict__ batch,
                       float* __restrict__ out, int n) {
    int g = blockIdx.x;
    int start = lower_bound_i(batch, n, g);
    int end   = lower_bound_i(batch, n, g + 1);
    int tid = threadIdx.x;
    int f   = tid % F3;
    int sub = tid / F3;
    float acc = 0.f;
    for (int i = start + sub; i < end; i += 8)
        acc += h[(size_t)i * F3 + f];
    __shared__ float red[256];
    red[tid] = acc;
    __syncthreads();
    if (tid < F3) {
        float s2 = 0.f;
        for (int j = 0; j < 8; ++j) s2 += red[j * F3 + tid];
        float cnt = (float)(end - start);
        out[g * F3 + tid] = (end > start) ? s2 / cnt : 0.f;
    }
}

extern "C" void kernel_launch(void* const* d_in, const int* in_sizes, int n_in,
                              void* d_out, int out_size, void* d_ws, size_t ws_size,
                              hipStream_t stream) {
    const float* x  = (const float*)d_in[0];
    const int*   ei = (const int*)d_in[1];      // (2, E): first E = src, next E = dst
    const int*   batch = (const int*)d_in[2];
    const float* W1 = (const float*)d_in[3];
    const float* b1 = (const float*)d_in[4];
    const float* W2 = (const float*)d_in[5];
    const float* b2 = (const float*)d_in[6];
    const float* W3 = (const float*)d_in[7];
    const float* b3 = (const float*)d_in[8];
    float* out = (float*)d_out;

    const int n = in_sizes[0] / F0;     // 100000
    const int e = in_sizes[1] / 2;      // 3200000
    const int* src = ei;
    const int* dst = ei + e;

    // workspace layout (4-byte words), same 84.1 MB footprint as the passing round-9 version:
    // cnt[NPAD] | dinv[NPAD] | ssrc[NPAD*WD] | bufA[NN*64] | bufB[NN*64]
    // small arrays live in ssrc's tail padding (nodes NN..NPAD-1 unused: 28160 words spare);
    // pairs (3.2M int2 = 25.6 MB) aliases bufA (dead until GEMM L1, which runs after k_place).
    int*   cnt    = (int*)d_ws;                        // NPAD
    float* dinv   = (float*)(cnt + NPAD);              // NPAD
    int*   ssrc   = (int*)(dinv + NPAD);               // NPAD*WD
    int*   bhist  = ssrc + (size_t)NN * WD;            // NBINS      (ssrc tail)
    int*   binoff = bhist + NBINS;                     // NBINS+1    (ssrc tail)
    int*   cursor = binoff + NBINS + 1;                // NBINS      (ssrc tail)
    float* bufA   = (float*)(ssrc + (size_t)NPAD * WD);// NN*64
    float* bufB   = bufA + (size_t)NN * 64;            // NN*64
    int2*  pairs  = (int2*)bufA;                       // aliases bufA

    const int B = 256;

    // ---- binned ELL adjacency build ----
    hipMemsetAsync(bhist, 0, NBINS * sizeof(int), stream);
    k_hist<<<256, B, 0, stream>>>(dst, bhist, e);
    k_scan<<<1, 1024, 0, stream>>>(bhist, binoff, cursor);
    k_part<<<(e + B - 1) / B, B, 0, stream>>>(src, dst, cursor, pairs, e);
    k_place<<<NBINS, B, 0, stream>>>(pairs, binoff, ssrc, cnt, dinv);

    // ---- layer 1 ----
    k_gemm<F0, F1, false><<<2048, B, 0, stream>>>(x, W1, dinv, bufA, n);
    k_gather<F1><<<((size_t)n * (F1 / 4) + B - 1) / B, B, 0, stream>>>(cnt, ssrc, dinv, bufA, b1, bufB, n);

    // ---- layer 2 ----
    k_gemm<F1, F2, true><<<2048, B, 0, stream>>>(bufB, W2, dinv, bufA, n);
    k_gather<F2><<<((size_t)n * (F2 / 4) + B - 1) / B, B, 0, stream>>>(cnt, ssrc, dinv, bufA, b2, bufB, n);

    // ---- layer 3 ----
    k_gemm<F2, F3, true><<<2048, B, 0, stream>>>(bufB, W3, dinv, bufA, n);
    k_gather<F3><<<((size_t)n * (F3 / 4) + B - 1) / B, B, 0, stream>>>(cnt, ssrc, dinv, bufA, b3, bufB, n);

    // ---- pooled mean ----
    k_pool<<<NG, B, 0, stream>>>(bufB, batch, out, n);
}

// Round 11
// 685.942 us; speedup vs baseline: 1.5902x; 1.5902x over previous
//
#include <hip/hip_runtime.h>

#define NN 100000
#define NE 3200000
#define NG 256
#define F0 128
#define F1 64
#define F2 64
#define F3 32
#define NPAD 100352   // 392 * 256, > NN+1
#define WD 80         // ELL row width; deg ~ Poisson(32), P(deg>=80) ~ 1e-13/node
#define NBINS 392     // NPAD >> 8
#define BSH 8         // 256 nodes per bin
#define CHUNK 12500   // NE / 256 blocks

// ---------------- Phase A: global per-bin histogram (LDS-staged) ----------------
__global__ __launch_bounds__(256) void k_hist(const int* __restrict__ dst,
                                              int* __restrict__ bhist, int e) {
    __shared__ int lh[NBINS];
    for (int i = threadIdx.x; i < NBINS; i += 256) lh[i] = 0;
    __syncthreads();
    for (int i = blockIdx.x * 256 + threadIdx.x; i < e; i += gridDim.x * 256)
        atomicAdd(&lh[dst[i] >> BSH], 1);
    __syncthreads();
    for (int i = threadIdx.x; i < NBINS; i += 256) {
        int v = lh[i];
        if (v) atomicAdd(&bhist[i], v);
    }
}

// ---------------- scan of 392 bin counts (one block of 512) ----------------
__global__ __launch_bounds__(512) void k_scan(const int* __restrict__ bhist,
                                              int* __restrict__ binoff,
                                              int* __restrict__ cursor) {
    __shared__ int s[512];
    int tid = threadIdx.x;
    int v = (tid < NBINS) ? bhist[tid] : 0;
    s[tid] = v;
    __syncthreads();
    for (int off = 1; off < 512; off <<= 1) {
        int t = (tid >= off) ? s[tid - off] : 0;
        __syncthreads();
        s[tid] += t;
        __syncthreads();
    }
    int excl = s[tid] - v;
    if (tid < NBINS) { binoff[tid] = excl; cursor[tid] = excl; }
    if (tid == 511) binoff[NBINS] = s[511];   // = e
}

// ---------------- Phase B: block-local counting sort into bin-grouped pair list ----------------
// Each block: LDS-hist its chunk, ONE reservation atomic per (block,bin), then dense run writes.
__global__ __launch_bounds__(256) void k_part2(const int* __restrict__ src,
                                               const int* __restrict__ dst,
                                               int* __restrict__ cursor,
                                               int2* __restrict__ pairs, int e) {
    __shared__ int lh[NBINS];
    __shared__ int base[NBINS];
    const int tid = threadIdx.x;
    const int beg = blockIdx.x * CHUNK;
    const int end = min(e, beg + CHUNK);
    for (int i = tid; i < NBINS; i += 256) lh[i] = 0;
    __syncthreads();
    for (int i = beg + tid; i < end; i += 256)
        atomicAdd(&lh[dst[i] >> BSH], 1);
    __syncthreads();
    for (int i = tid; i < NBINS; i += 256) {
        int v = lh[i];
        base[i] = v ? atomicAdd(&cursor[i], v) : 0;   // one global atomic per (block,bin)
        lh[i] = 0;                                    // reuse as local run cursor
    }
    __syncthreads();
    for (int i = beg + tid; i < end; i += 256) {
        int d = dst[i];
        int bin = d >> BSH;
        int pos = base[bin] + atomicAdd(&lh[bin], 1); // LDS atomic, dense run write
        pairs[pos] = make_int2(src[i], d);
    }
}

// ---------------- Phase C: per-bin ELL placement via LDS counters; fuses cnt+dinv ----------------
__global__ __launch_bounds__(256) void k_place(const int2* __restrict__ pairs,
                                               const int* __restrict__ binoff,
                                               int* __restrict__ ssrc,
                                               int* __restrict__ cnt,
                                               float* __restrict__ dinv) {
    __shared__ int lc[256];
    const int b = blockIdx.x;
    const int tid = threadIdx.x;
    lc[tid] = 0;
    __syncthreads();
    int beg = binoff[b], end = binoff[b + 1];
    for (int i = beg + tid; i < end; i += 256) {
        int2 p = pairs[i];
        int pos = atomicAdd(&lc[p.y & 255], 1);
        if (pos < WD) ssrc[(size_t)p.y * WD + pos] = p.x;
    }
    __syncthreads();
    int node = (b << BSH) + tid;     // < NPAD by construction
    int c = lc[tid];
    cnt[node] = c;
    dinv[node] = rsqrtf((float)(c + 1));   // +1 self-loop
}

// ---------------- GEMM: out[nn,:] = ((relu?)x[nn,:] @ W) * dinv[nn] ----------------
template<int F_IN, int F_OUT, bool RELU_IN>
__global__ __launch_bounds__(256) void k_gemm(const float* __restrict__ x,
                                              const float* __restrict__ W,
                                              const float* __restrict__ dinv,
                                              float* __restrict__ out, int n) {
    constexpr int NPB = 256 / F_OUT;   // nodes per block-tile
    __shared__ float Wl[F_IN * F_OUT];
    __shared__ float Xl[NPB * F_IN];
    const int tid = threadIdx.x;
    for (int i = tid; i < F_IN * F_OUT; i += 256) Wl[i] = W[i];

    const int nl = tid / F_OUT;
    const int f  = tid % F_OUT;
    const int ntiles = (n + NPB - 1) / NPB;

    for (int tile = blockIdx.x; tile < ntiles; tile += gridDim.x) {
        const int n0 = tile * NPB;
        __syncthreads();
        for (int i = tid; i < NPB * F_IN; i += 256) {
            int nn = n0 + i / F_IN;
            float v = (nn < n) ? x[(size_t)nn * F_IN + (i % F_IN)] : 0.f;
            Xl[i] = RELU_IN ? fmaxf(v, 0.f) : v;
        }
        __syncthreads();
        const int nn = n0 + nl;
        if (nn < n) {
            const int xb = nl * F_IN;
            float a0 = 0.f, a1 = 0.f, a2 = 0.f, a3 = 0.f;
#pragma unroll
            for (int k = 0; k < F_IN; k += 4) {
                a0 = fmaf(Xl[xb + k + 0], Wl[(k + 0) * F_OUT + f], a0);
                a1 = fmaf(Xl[xb + k + 1], Wl[(k + 1) * F_OUT + f], a1);
                a2 = fmaf(Xl[xb + k + 2], Wl[(k + 2) * F_OUT + f], a2);
                a3 = fmaf(Xl[xb + k + 3], Wl[(k + 3) * F_OUT + f], a3);
            }
            out[(size_t)nn * F_OUT + f] = ((a0 + a1) + (a2 + a3)) * dinv[nn];
        }
    }
}

// ---------------- ELL gather: out[d] = b + dinv[d] * (h'[d] + sum_{s in N(d)} h'[s]) ----------------
template<int F>
__global__ __launch_bounds__(256) void k_gather(const int* __restrict__ cnt,
                                                const int* __restrict__ ssrc,
                                                const float* __restrict__ dinv,
                                                const float* __restrict__ h,
                                                const float* __restrict__ b,
                                                float* __restrict__ out, int n) {
    constexpr int G = F / 4;
    int t = blockIdx.x * blockDim.x + threadIdx.x;
    int node = t / G;
    int g    = t % G;
    if (node >= n) return;
    float dd = dinv[node];
    float4 acc = ((const float4*)(h + (size_t)node * F))[g];   // self term h'[d]
    int c = cnt[node]; if (c > WD) c = WD;
    const int* row = ssrc + (size_t)node * WD;
    int j = 0;
    for (; j + 4 <= c; j += 4) {
        int4 s4 = *(const int4*)(row + j);
        float4 v0 = ((const float4*)(h + (size_t)s4.x * F))[g];
        float4 v1 = ((const float4*)(h + (size_t)s4.y * F))[g];
        float4 v2 = ((const float4*)(h + (size_t)s4.z * F))[g];
        float4 v3 = ((const float4*)(h + (size_t)s4.w * F))[g];
        acc.x += (v0.x + v1.x) + (v2.x + v3.x);
        acc.y += (v0.y + v1.y) + (v2.y + v3.y);
        acc.z += (v0.z + v1.z) + (v2.z + v3.z);
        acc.w += (v0.w + v1.w) + (v2.w + v3.w);
    }
    for (; j < c; ++j) {
        int s = row[j];
        float4 v = ((const float4*)(h + (size_t)s * F))[g];
        acc.x += v.x; acc.y += v.y; acc.z += v.z; acc.w += v.w;
    }
    float4 bb = ((const float4*)b)[g];
    float4 o;
    o.x = fmaf(dd, acc.x, bb.x);
    o.y = fmaf(dd, acc.y, bb.y);
    o.z = fmaf(dd, acc.z, bb.z);
    o.w = fmaf(dd, acc.w, bb.w);
    ((float4*)(out + (size_t)node * F))[g] = o;
}

// ---------------- pooled mean over sorted batch ----------------
__device__ __forceinline__ int lower_bound_i(const int* __restrict__ a, int n, int key) {
    int lo = 0, hi = n;
    while (lo < hi) { int mid = (lo + hi) >> 1; if (a[mid] < key) lo = mid + 1; else hi = mid; }
    return lo;
}

__global__ void k_pool(const float* __restrict__ h, const int* __restrict__ batch,
                       float* __restrict__ out, int n) {
    int g = blockIdx.x;
    int start = lower_bound_i(batch, n, g);
    int end   = lower_bound_i(batch, n, g + 1);
    int tid = threadIdx.x;
    int f   = tid % F3;
    int sub = tid / F3;
    float acc = 0.f;
    for (int i = start + sub; i < end; i += 8)
        acc += h[(size_t)i * F3 + f];
    __shared__ float red[256];
    red[tid] = acc;
    __syncthreads();
    if (tid < F3) {
        float s2 = 0.f;
        for (int j = 0; j < 8; ++j) s2 += red[j * F3 + tid];
        float cnt = (float)(end - start);
        out[g * F3 + tid] = (end > start) ? s2 / cnt : 0.f;
    }
}

extern "C" void kernel_launch(void* const* d_in, const int* in_sizes, int n_in,
                              void* d_out, int out_size, void* d_ws, size_t ws_size,
                              hipStream_t stream) {
    const float* x  = (const float*)d_in[0];
    const int*   ei = (const int*)d_in[1];      // (2, E): first E = src, next E = dst
    const int*   batch = (const int*)d_in[2];
    const float* W1 = (const float*)d_in[3];
    const float* b1 = (const float*)d_in[4];
    const float* W2 = (const float*)d_in[5];
    const float* b2 = (const float*)d_in[6];
    const float* W3 = (const float*)d_in[7];
    const float* b3 = (const float*)d_in[8];
    float* out = (float*)d_out;

    const int n = in_sizes[0] / F0;     // 100000
    const int e = in_sizes[1] / 2;      // 3200000
    const int* src = ei;
    const int* dst = ei + e;

    // workspace layout (4-byte words), same 84.1 MB footprint as the passing round-9 version:
    // cnt[NPAD] | dinv[NPAD] | ssrc[NPAD*WD] | bufA[NN*64] | bufB[NN*64]
    // small arrays live in ssrc's tail padding (nodes NN..NPAD-1 unused: 28160 words spare);
    // pairs (3.2M int2 = 25.6 MB) aliases bufA (dead until GEMM L1, which runs after k_place).
    int*   cnt    = (int*)d_ws;                        // NPAD
    float* dinv   = (float*)(cnt + NPAD);              // NPAD
    int*   ssrc   = (int*)(dinv + NPAD);               // NPAD*WD
    int*   bhist  = ssrc + (size_t)NN * WD;            // NBINS      (ssrc tail)
    int*   binoff = bhist + NBINS;                     // NBINS+1    (ssrc tail)
    int*   cursor = binoff + NBINS + 1;                // NBINS      (ssrc tail)
    float* bufA   = (float*)(ssrc + (size_t)NPAD * WD);// NN*64
    float* bufB   = bufA + (size_t)NN * 64;            // NN*64
    int2*  pairs  = (int2*)bufA;                       // aliases bufA

    const int B = 256;

    // ---- binned ELL adjacency build (block-local counting sort) ----
    hipMemsetAsync(bhist, 0, NBINS * sizeof(int), stream);
    k_hist<<<256, B, 0, stream>>>(dst, bhist, e);
    k_scan<<<1, 512, 0, stream>>>(bhist, binoff, cursor);
    k_part2<<<(e + CHUNK - 1) / CHUNK, B, 0, stream>>>(src, dst, cursor, pairs, e);
    k_place<<<NBINS, B, 0, stream>>>(pairs, binoff, ssrc, cnt, dinv);

    // ---- layer 1 ----
    k_gemm<F0, F1, false><<<2048, B, 0, stream>>>(x, W1, dinv, bufA, n);
    k_gather<F1><<<((size_t)n * (F1 / 4) + B - 1) / B, B, 0, stream>>>(cnt, ssrc, dinv, bufA, b1, bufB, n);

    // ---- layer 2 ----
    k_gemm<F1, F2, true><<<2048, B, 0, stream>>>(bufB, W2, dinv, bufA, n);
    k_gather<F2><<<((size_t)n * (F2 / 4) + B - 1) / B, B, 0, stream>>>(cnt, ssrc, dinv, bufA, b2, bufB, n);

    // ---- layer 3 ----
    k_gemm<F2, F3, true><<<2048, B, 0, stream>>>(bufB, W3, dinv, bufA, n);
    k_gather<F3><<<((size_t)n * (F3 / 4) + B - 1) / B, B, 0, stream>>>(cnt, ssrc, dinv, bufA, b3, bufB, n);

    // ---- pooled mean ----
    k_pool<<<NG, B, 0, stream>>>(bufB, batch, out, n);
}

// Round 12
// 559.498 us; speedup vs baseline: 1.9495x; 1.2260x over previous
//
#include <hip/hip_runtime.h>
#include <hip/hip_bf16.h>

#define NN 100000
#define NE 3200000
#define NG 256
#define F0 128
#define F1 64
#define F2 64
#define F3 32
#define NPAD 100352   // 392 * 256, > NN+1
#define WD 80         // ELL row width; deg ~ Poisson(32), P(deg>=80) ~ 1e-13/node
#define NBINS 392     // NPAD >> 8
#define BSH 8         // 256 nodes per bin
#define CHUNK 12500   // NE / 256 blocks

// ---------------- Phase A: global per-bin histogram (LDS-staged) ----------------
__global__ __launch_bounds__(256) void k_hist(const int* __restrict__ dst,
                                              int* __restrict__ bhist, int e) {
    __shared__ int lh[NBINS];
    for (int i = threadIdx.x; i < NBINS; i += 256) lh[i] = 0;
    __syncthreads();
    for (int i = blockIdx.x * 256 + threadIdx.x; i < e; i += gridDim.x * 256)
        atomicAdd(&lh[dst[i] >> BSH], 1);
    __syncthreads();
    for (int i = threadIdx.x; i < NBINS; i += 256) {
        int v = lh[i];
        if (v) atomicAdd(&bhist[i], v);
    }
}

// ---------------- scan of 392 bin counts (one block of 512) ----------------
__global__ __launch_bounds__(512) void k_scan(const int* __restrict__ bhist,
                                              int* __restrict__ binoff,
                                              int* __restrict__ cursor) {
    __shared__ int s[512];
    int tid = threadIdx.x;
    int v = (tid < NBINS) ? bhist[tid] : 0;
    s[tid] = v;
    __syncthreads();
    for (int off = 1; off < 512; off <<= 1) {
        int t = (tid >= off) ? s[tid - off] : 0;
        __syncthreads();
        s[tid] += t;
        __syncthreads();
    }
    int excl = s[tid] - v;
    if (tid < NBINS) { binoff[tid] = excl; cursor[tid] = excl; }
    if (tid == 511) binoff[NBINS] = s[511];   // = e
}

// ---------------- Phase B: block-local counting sort into bin-grouped PACKED list ----------------
// pack = (src << 8) | (dst & 255); src < 2^17, so pack < 2^25. Halves pair traffic vs int2.
__global__ __launch_bounds__(256) void k_part2(const int* __restrict__ src,
                                               const int* __restrict__ dst,
                                               int* __restrict__ cursor,
                                               int* __restrict__ pairs, int e) {
    __shared__ int lh[NBINS];
    __shared__ int base[NBINS];
    const int tid = threadIdx.x;
    const int beg = blockIdx.x * CHUNK;
    const int end = min(e, beg + CHUNK);
    for (int i = tid; i < NBINS; i += 256) lh[i] = 0;
    __syncthreads();
    for (int i = beg + tid; i < end; i += 256)
        atomicAdd(&lh[dst[i] >> BSH], 1);
    __syncthreads();
    for (int i = tid; i < NBINS; i += 256) {
        int v = lh[i];
        base[i] = v ? atomicAdd(&cursor[i], v) : 0;   // one global atomic per (block,bin)
        lh[i] = 0;                                    // reuse as local run cursor
    }
    __syncthreads();
    for (int i = beg + tid; i < end; i += 256) {
        int d = dst[i];
        int bin = d >> BSH;
        int pos = base[bin] + atomicAdd(&lh[bin], 1); // LDS atomic, dense run write
        pairs[pos] = (src[i] << 8) | (d & 255);
    }
}

// ---------------- Phase C: per-bin ELL placement via LDS counters; fuses cnt+dinv ----------------
__global__ __launch_bounds__(256) void k_place(const int* __restrict__ pairs,
                                               const int* __restrict__ binoff,
                                               int* __restrict__ ssrc,
                                               int* __restrict__ cnt,
                                               float* __restrict__ dinv) {
    __shared__ int lc[256];
    const int b = blockIdx.x;
    const int tid = threadIdx.x;
    lc[tid] = 0;
    __syncthreads();
    int beg = binoff[b], end = binoff[b + 1];
    for (int i = beg + tid; i < end; i += 256) {
        int pk = pairs[i];
        int node = (b << BSH) + (pk & 255);
        int pos = atomicAdd(&lc[pk & 255], 1);
        if (pos < WD) ssrc[(size_t)node * WD + pos] = pk >> 8;
    }
    __syncthreads();
    int node = (b << BSH) + tid;     // < NPAD by construction
    int c = lc[tid];
    cnt[node] = c;
    dinv[node] = rsqrtf((float)(c + 1));   // +1 self-loop
}

// ---------------- GEMM: out[nn,:] = ((relu?)x[nn,:] @ W) * dinv[nn], f32 or bf16 out ----------------
template<int F_IN, int F_OUT, bool RELU_IN, bool OBF16>
__global__ __launch_bounds__(256) void k_gemm(const float* __restrict__ x,
                                              const float* __restrict__ W,
                                              const float* __restrict__ dinv,
                                              void* __restrict__ outv, int n) {
    constexpr int NPB = 256 / F_OUT;   // nodes per block-tile
    __shared__ float Wl[F_IN * F_OUT];
    __shared__ float Xl[NPB * F_IN];
    const int tid = threadIdx.x;
    for (int i = tid; i < F_IN * F_OUT; i += 256) Wl[i] = W[i];

    const int nl = tid / F_OUT;
    const int f  = tid % F_OUT;
    const int ntiles = (n + NPB - 1) / NPB;

    for (int tile = blockIdx.x; tile < ntiles; tile += gridDim.x) {
        const int n0 = tile * NPB;
        __syncthreads();
        for (int i = tid; i < NPB * F_IN; i += 256) {
            int nn = n0 + i / F_IN;
            float v = (nn < n) ? x[(size_t)nn * F_IN + (i % F_IN)] : 0.f;
            Xl[i] = RELU_IN ? fmaxf(v, 0.f) : v;
        }
        __syncthreads();
        const int nn = n0 + nl;
        if (nn < n) {
            const int xb = nl * F_IN;
            float a0 = 0.f, a1 = 0.f, a2 = 0.f, a3 = 0.f;
#pragma unroll
            for (int k = 0; k < F_IN; k += 4) {
                a0 = fmaf(Xl[xb + k + 0], Wl[(k + 0) * F_OUT + f], a0);
                a1 = fmaf(Xl[xb + k + 1], Wl[(k + 1) * F_OUT + f], a1);
                a2 = fmaf(Xl[xb + k + 2], Wl[(k + 2) * F_OUT + f], a2);
                a3 = fmaf(Xl[xb + k + 3], Wl[(k + 3) * F_OUT + f], a3);
            }
            float val = ((a0 + a1) + (a2 + a3)) * dinv[nn];
            if (OBF16)
                ((__hip_bfloat16*)outv)[(size_t)nn * F_OUT + f] = __float2bfloat16(val);
            else
                ((float*)outv)[(size_t)nn * F_OUT + f] = val;
        }
    }
}

// ---------------- bf16x4 -> float4 unpack ----------------
__device__ __forceinline__ float4 bf4(uint2 u) {
    float4 r;
    r.x = __uint_as_float((u.x & 0xffffu) << 16);
    r.y = __uint_as_float(u.x & 0xffff0000u);
    r.z = __uint_as_float((u.y & 0xffffu) << 16);
    r.w = __uint_as_float(u.y & 0xffff0000u);
    return r;
}

template<bool BF16IN, int G>
__device__ __forceinline__ float4 ldrow(const void* hv, int node, int g) {
    if constexpr (BF16IN)
        return bf4(((const uint2*)hv)[(size_t)node * G + g]);
    else
        return ((const float4*)hv)[(size_t)node * G + g];
}

// ---------------- ELL gather: out[d] = b + dinv[d] * (h'[d] + sum_{s in N(d)} h'[s]) ----------------
// h' rows prescaled by dinv_s; f32 accumulate; f32 out.
template<int F, bool BF16IN>
__global__ __launch_bounds__(256) void k_gather(const int* __restrict__ cnt,
                                                const int* __restrict__ ssrc,
                                                const float* __restrict__ dinv,
                                                const void* __restrict__ hv,
                                                const float* __restrict__ b,
                                                float* __restrict__ out, int n) {
    constexpr int G = F / 4;
    int t = blockIdx.x * blockDim.x + threadIdx.x;
    int node = t / G;
    int g    = t % G;
    if (node >= n) return;
    float dd = dinv[node];
    float4 acc = ldrow<BF16IN, G>(hv, node, g);   // self term h'[d]
    int c = cnt[node]; if (c > WD) c = WD;
    const int* row = ssrc + (size_t)node * WD;
    int j = 0;
    for (; j + 8 <= c; j += 8) {
        int4 i0 = *(const int4*)(row + j);
        int4 i1 = *(const int4*)(row + j + 4);
        float4 v0 = ldrow<BF16IN, G>(hv, i0.x, g);
        float4 v1 = ldrow<BF16IN, G>(hv, i0.y, g);
        float4 v2 = ldrow<BF16IN, G>(hv, i0.z, g);
        float4 v3 = ldrow<BF16IN, G>(hv, i0.w, g);
        float4 v4 = ldrow<BF16IN, G>(hv, i1.x, g);
        float4 v5 = ldrow<BF16IN, G>(hv, i1.y, g);
        float4 v6 = ldrow<BF16IN, G>(hv, i1.z, g);
        float4 v7 = ldrow<BF16IN, G>(hv, i1.w, g);
        acc.x += ((v0.x + v1.x) + (v2.x + v3.x)) + ((v4.x + v5.x) + (v6.x + v7.x));
        acc.y += ((v0.y + v1.y) + (v2.y + v3.y)) + ((v4.y + v5.y) + (v6.y + v7.y));
        acc.z += ((v0.z + v1.z) + (v2.z + v3.z)) + ((v4.z + v5.z) + (v6.z + v7.z));
        acc.w += ((v0.w + v1.w) + (v2.w + v3.w)) + ((v4.w + v5.w) + (v6.w + v7.w));
    }
    for (; j + 4 <= c; j += 4) {
        int4 i0 = *(const int4*)(row + j);
        float4 v0 = ldrow<BF16IN, G>(hv, i0.x, g);
        float4 v1 = ldrow<BF16IN, G>(hv, i0.y, g);
        float4 v2 = ldrow<BF16IN, G>(hv, i0.z, g);
        float4 v3 = ldrow<BF16IN, G>(hv, i0.w, g);
        acc.x += (v0.x + v1.x) + (v2.x + v3.x);
        acc.y += (v0.y + v1.y) + (v2.y + v3.y);
        acc.z += (v0.z + v1.z) + (v2.z + v3.z);
        acc.w += (v0.w + v1.w) + (v2.w + v3.w);
    }
    for (; j < c; ++j) {
        float4 v = ldrow<BF16IN, G>(hv, row[j], g);
        acc.x += v.x; acc.y += v.y; acc.z += v.z; acc.w += v.w;
    }
    float4 bb = ((const float4*)b)[g];
    float4 o;
    o.x = fmaf(dd, acc.x, bb.x);
    o.y = fmaf(dd, acc.y, bb.y);
    o.z = fmaf(dd, acc.z, bb.z);
    o.w = fmaf(dd, acc.w, bb.w);
    ((float4*)(out + (size_t)node * F))[g] = o;
}

// ---------------- pooled mean over sorted batch ----------------
__device__ __forceinline__ int lower_bound_i(const int* __restrict__ a, int n, int key) {
    int lo = 0, hi = n;
    while (lo < hi) { int mid = (lo + hi) >> 1; if (a[mid] < key) lo = mid + 1; else hi = mid; }
    return lo;
}

__global__ void k_pool(const float* __restrict__ h, const int* __restrict__ batch,
                       float* __restrict__ out, int n) {
    int g = blockIdx.x;
    int start = lower_bound_i(batch, n, g);
    int end   = lower_bound_i(batch, n, g + 1);
    int tid = threadIdx.x;
    int f   = tid % F3;
    int sub = tid / F3;
    float acc = 0.f;
    for (int i = start + sub; i < end; i += 8)
        acc += h[(size_t)i * F3 + f];
    __shared__ float red[256];
    red[tid] = acc;
    __syncthreads();
    if (tid < F3) {
        float s2 = 0.f;
        for (int j = 0; j < 8; ++j) s2 += red[j * F3 + tid];
        float cnt = (float)(end - start);
        out[g * F3 + tid] = (end > start) ? s2 / cnt : 0.f;
    }
}

extern "C" void kernel_launch(void* const* d_in, const int* in_sizes, int n_in,
                              void* d_out, int out_size, void* d_ws, size_t ws_size,
                              hipStream_t stream) {
    const float* x  = (const float*)d_in[0];
    const int*   ei = (const int*)d_in[1];      // (2, E): first E = src, next E = dst
    const int*   batch = (const int*)d_in[2];
    const float* W1 = (const float*)d_in[3];
    const float* b1 = (const float*)d_in[4];
    const float* W2 = (const float*)d_in[5];
    const float* b2 = (const float*)d_in[6];
    const float* W3 = (const float*)d_in[7];
    const float* b3 = (const float*)d_in[8];
    float* out = (float*)d_out;

    const int n = in_sizes[0] / F0;     // 100000
    const int e = in_sizes[1] / 2;      // 3200000
    const int* src = ei;
    const int* dst = ei + e;

    // workspace (4-byte words), same 84.1 MB footprint as round 11:
    // cnt[NPAD] | dinv[NPAD] | ssrc[NPAD*WD] (+tail: bhist/binoff/cursor) | bufA[NN*64] | bufB[NN*64]
    // bufA region life: pairs(int, 12.8MB) -> h1' bf16 -> h2' bf16 -> h3' f32
    // bufB region life: gather1 out f32 -> gather2 out f32 -> gather3 out f32 (pool input)
    int*   cnt    = (int*)d_ws;                        // NPAD
    float* dinv   = (float*)(cnt + NPAD);              // NPAD
    int*   ssrc   = (int*)(dinv + NPAD);               // NPAD*WD
    int*   bhist  = ssrc + (size_t)NN * WD;            // NBINS      (ssrc tail)
    int*   binoff = bhist + NBINS;                     // NBINS+1    (ssrc tail)
    int*   cursor = binoff + NBINS + 1;                // NBINS      (ssrc tail)
    float* bufA   = (float*)(ssrc + (size_t)NPAD * WD);// NN*64 words
    float* bufB   = bufA + (size_t)NN * 64;            // NN*64 words
    int*             pairs = (int*)bufA;               // alias
    __hip_bfloat16*  hbfA  = (__hip_bfloat16*)bufA;    // alias

    const int B = 256;

    // ---- binned ELL adjacency build (block-local counting sort, packed pairs) ----
    hipMemsetAsync(bhist, 0, NBINS * sizeof(int), stream);
    k_hist<<<256, B, 0, stream>>>(dst, bhist, e);
    k_scan<<<1, 512, 0, stream>>>(bhist, binoff, cursor);
    k_part2<<<(e + CHUNK - 1) / CHUNK, B, 0, stream>>>(src, dst, cursor, pairs, e);
    k_place<<<NBINS, B, 0, stream>>>(pairs, binoff, ssrc, cnt, dinv);

    // ---- layer 1: h1' bf16 = (x@W1)*dinv ; gather -> bufB f32 ----
    k_gemm<F0, F1, false, true><<<2048, B, 0, stream>>>(x, W1, dinv, hbfA, n);
    k_gather<F1, true><<<((size_t)n * (F1 / 4) + B - 1) / B, B, 0, stream>>>(cnt, ssrc, dinv, hbfA, b1, bufB, n);

    // ---- layer 2 ----
    k_gemm<F1, F2, true, true><<<2048, B, 0, stream>>>(bufB, W2, dinv, hbfA, n);
    k_gather<F2, true><<<((size_t)n * (F2 / 4) + B - 1) / B, B, 0, stream>>>(cnt, ssrc, dinv, hbfA, b2, bufB, n);

    // ---- layer 3 (f32 h3') ----
    k_gemm<F2, F3, true, false><<<2048, B, 0, stream>>>(bufB, W3, dinv, bufA, n);
    k_gather<F3, false><<<((size_t)n * (F3 / 4) + B - 1) / B, B, 0, stream>>>(cnt, ssrc, dinv, bufA, b3, bufB, n);

    // ---- pooled mean ----
    k_pool<<<NG, B, 0, stream>>>(bufB, batch, out, n);
}

// Round 17
// 518.686 us; speedup vs baseline: 2.1029x; 1.0787x over previous
//
#include <hip/hip_runtime.h>
#include <hip/hip_bf16.h>

#define NN 100000
#define NE 3200000
#define NG 256
#define F0 128
#define F1 64
#define F2 64
#define F3 32
#define NPAD 100352   // 392 * 256, > NN+1
#define WD 80         // ELL row width; deg ~ Poisson(32), P(deg>=80) ~ 1e-13/node
#define NBINS 392     // NPAD >> 8
#define BSH 8         // 256 nodes per bin
#define CHUNK 12500   // NE / 256 blocks

// f32 -> bf16 round-to-nearest-even (bit-level; same as __float2bfloat16 for finite vals)
__device__ __forceinline__ unsigned short f2bf(float f) {
    unsigned int u = __float_as_uint(f);
    return (unsigned short)((u + 0x7fffu + ((u >> 16) & 1u)) >> 16);
}

// ---------------- Phase A: global per-bin histogram (LDS-staged) ----------------
__global__ __launch_bounds__(256) void k_hist(const int* __restrict__ dst,
                                              int* __restrict__ bhist, int e) {
    __shared__ int lh[NBINS];
    for (int i = threadIdx.x; i < NBINS; i += 256) lh[i] = 0;
    __syncthreads();
    for (int i = blockIdx.x * 256 + threadIdx.x; i < e; i += gridDim.x * 256)
        atomicAdd(&lh[dst[i] >> BSH], 1);
    __syncthreads();
    for (int i = threadIdx.x; i < NBINS; i += 256) {
        int v = lh[i];
        if (v) atomicAdd(&bhist[i], v);
    }
}

// ---------------- scan of 392 bin counts (one block of 512) ----------------
__global__ __launch_bounds__(512) void k_scan(const int* __restrict__ bhist,
                                              int* __restrict__ binoff,
                                              int* __restrict__ cursor) {
    __shared__ int s[512];
    int tid = threadIdx.x;
    int v = (tid < NBINS) ? bhist[tid] : 0;
    s[tid] = v;
    __syncthreads();
    for (int off = 1; off < 512; off <<= 1) {
        int t = (tid >= off) ? s[tid - off] : 0;
        __syncthreads();
        s[tid] += t;
        __syncthreads();
    }
    int excl = s[tid] - v;
    if (tid < NBINS) { binoff[tid] = excl; cursor[tid] = excl; }
    if (tid == 511) binoff[NBINS] = s[511];   // = e
}

// ---------------- Phase B: block-local counting sort into bin-grouped PACKED list ----------------
// pack = (src << 8) | (dst & 255); src < 2^17, so pack < 2^25.
__global__ __launch_bounds__(256) void k_part2(const int* __restrict__ src,
                                               const int* __restrict__ dst,
                                               int* __restrict__ cursor,
                                               int* __restrict__ pairs, int e) {
    __shared__ int lh[NBINS];
    __shared__ int base[NBINS];
    const int tid = threadIdx.x;
    const int beg = blockIdx.x * CHUNK;
    const int end = min(e, beg + CHUNK);
    for (int i = tid; i < NBINS; i += 256) lh[i] = 0;
    __syncthreads();
    for (int i = beg + tid; i < end; i += 256)
        atomicAdd(&lh[dst[i] >> BSH], 1);
    __syncthreads();
    for (int i = tid; i < NBINS; i += 256) {
        int v = lh[i];
        base[i] = v ? atomicAdd(&cursor[i], v) : 0;   // one global atomic per (block,bin)
        lh[i] = 0;                                    // reuse as local run cursor
    }
    __syncthreads();
    for (int i = beg + tid; i < end; i += 256) {
        int d = dst[i];
        int bin = d >> BSH;
        int pos = base[bin] + atomicAdd(&lh[bin], 1); // LDS atomic, dense run write
        pairs[pos] = (src[i] << 8) | (d & 255);
    }
}

// ---------------- Phase C: per-bin ELL placement via LDS counters; fuses cnt+dinv ----------------
__global__ __launch_bounds__(256) void k_place(const int* __restrict__ pairs,
                                               const int* __restrict__ binoff,
                                               int* __restrict__ ssrc,
                                               int* __restrict__ cnt,
                                               float* __restrict__ dinv) {
    __shared__ int lc[256];
    const int b = blockIdx.x;
    const int tid = threadIdx.x;
    lc[tid] = 0;
    __syncthreads();
    int beg = binoff[b], end = binoff[b + 1];
    for (int i = beg + tid; i < end; i += 256) {
        int pk = pairs[i];
        int node = (b << BSH) + (pk & 255);
        int pos = atomicAdd(&lc[pk & 255], 1);
        if (pos < WD) ssrc[(size_t)node * WD + pos] = pk >> 8;
    }
    __syncthreads();
    int node = (b << BSH) + tid;     // < NPAD by construction
    int c = lc[tid];
    cnt[node] = c;
    dinv[node] = rsqrtf((float)(c + 1));   // +1 self-loop
}

// ---------------- register-tiled GEMM: out[nn,:] = ((relu?)x[nn,:] @ W) * dinv[nn] ----------------
// Thread tile: TM=4 nodes x TN=4 feats in 16 regs; per k: 2 x ds_read_b128 -> 16 FMAs.
template<int F_IN, int F_OUT, bool RELU_IN, bool OBF16>
__global__ __launch_bounds__(256) void k_gemm(const float* __restrict__ x,
                                              const float* __restrict__ W,
                                              const float* __restrict__ dinv,
                                              void* __restrict__ outv, int n) {
    constexpr int KC  = 32;            // K-chunk
    constexpr int TN  = 4, TM = 4;
    constexpr int NTF = F_OUT / TN;    // threads along features
    constexpr int NTN = 256 / NTF;     // threads along nodes
    constexpr int BN  = NTN * TM;      // nodes per block tile (64 or 128)
    constexpr int XST = BN + 4;        // Xl stride: keeps 16B alignment for b128 reads
    __shared__ float Wl[F_IN * F_OUT];
    __shared__ float Xl[KC * XST];
    const int tid = threadIdx.x;
    for (int i = tid; i < F_IN * F_OUT; i += 256) Wl[i] = W[i];

    const int f0  = (tid % NTF) * TN;
    const int nn0 = (tid / NTF) * TM;
    const int n0  = blockIdx.x * BN;

    float acc[TM][TN];
#pragma unroll
    for (int a = 0; a < TM; ++a)
#pragma unroll
        for (int q = 0; q < TN; ++q) acc[a][q] = 0.f;

    for (int kc = 0; kc < F_IN; kc += KC) {
        __syncthreads();
        // stage Xl[k][node], coalesced global reads (consecutive lanes -> consecutive k)
        for (int i = tid; i < KC * BN; i += 256) {
            int node = i / KC;
            int k    = i % KC;
            int nn   = n0 + node;
            float v = (nn < n) ? x[(size_t)nn * F_IN + kc + k] : 0.f;
            Xl[k * XST + node] = RELU_IN ? fmaxf(v, 0.f) : v;
        }
        __syncthreads();
#pragma unroll
        for (int k = 0; k < KC; ++k) {
            float4 xv = *(const float4*)&Xl[k * XST + nn0];
            float4 wv = *(const float4*)&Wl[(kc + k) * F_OUT + f0];
            acc[0][0] = fmaf(xv.x, wv.x, acc[0][0]);
            acc[0][1] = fmaf(xv.x, wv.y, acc[0][1]);
            acc[0][2] = fmaf(xv.x, wv.z, acc[0][2]);
            acc[0][3] = fmaf(xv.x, wv.w, acc[0][3]);
            acc[1][0] = fmaf(xv.y, wv.x, acc[1][0]);
            acc[1][1] = fmaf(xv.y, wv.y, acc[1][1]);
            acc[1][2] = fmaf(xv.y, wv.z, acc[1][2]);
            acc[1][3] = fmaf(xv.y, wv.w, acc[1][3]);
            acc[2][0] = fmaf(xv.z, wv.x, acc[2][0]);
            acc[2][1] = fmaf(xv.z, wv.y, acc[2][1]);
            acc[2][2] = fmaf(xv.z, wv.z, acc[2][2]);
            acc[2][3] = fmaf(xv.z, wv.w, acc[2][3]);
            acc[3][0] = fmaf(xv.w, wv.x, acc[3][0]);
            acc[3][1] = fmaf(xv.w, wv.y, acc[3][1]);
            acc[3][2] = fmaf(xv.w, wv.z, acc[3][2]);
            acc[3][3] = fmaf(xv.w, wv.w, acc[3][3]);
        }
    }

#pragma unroll
    for (int a = 0; a < TM; ++a) {
        int nn = n0 + nn0 + a;
        if (nn >= n) break;
        float d = dinv[nn];
        if (OBF16) {
            ushort4 st;
            st.x = f2bf(acc[a][0] * d);
            st.y = f2bf(acc[a][1] * d);
            st.z = f2bf(acc[a][2] * d);
            st.w = f2bf(acc[a][3] * d);
            *(ushort4*)((unsigned short*)outv + (size_t)nn * F_OUT + f0) = st;
        } else {
            float4 st = make_float4(acc[a][0] * d, acc[a][1] * d, acc[a][2] * d, acc[a][3] * d);
            *(float4*)((float*)outv + (size_t)nn * F_OUT + f0) = st;
        }
    }
}

// ---------------- bf16x4 -> float4 unpack ----------------
__device__ __forceinline__ float4 bf4(uint2 u) {
    float4 r;
    r.x = __uint_as_float((u.x & 0xffffu) << 16);
    r.y = __uint_as_float(u.x & 0xffff0000u);
    r.z = __uint_as_float((u.y & 0xffffu) << 16);
    r.w = __uint_as_float(u.y & 0xffff0000u);
    return r;
}

template<bool BF16IN, int G>
__device__ __forceinline__ float4 ldrow(const void* hv, int node, int g) {
    if constexpr (BF16IN)
        return bf4(((const uint2*)hv)[(size_t)node * G + g]);
    else
        return ((const float4*)hv)[(size_t)node * G + g];
}

// ---------------- ELL gather: out[d] = b + dinv[d] * (h'[d] + sum_{s in N(d)} h'[s]) ----------------
template<int F, bool BF16IN>
__global__ __launch_bounds__(256) void k_gather(const int* __restrict__ cnt,
                                                const int* __restrict__ ssrc,
                                                const float* __restrict__ dinv,
                                                const void* __restrict__ hv,
                                                const float* __restrict__ b,
                                                float* __restrict__ out, int n) {
    constexpr int G = F / 4;
    int t = blockIdx.x * blockDim.x + threadIdx.x;
    int node = t / G;
    int g    = t % G;
    if (node >= n) return;
    float dd = dinv[node];
    float4 acc = ldrow<BF16IN, G>(hv, node, g);   // self term h'[d]
    int c = cnt[node]; if (c > WD) c = WD;
    const int* row = ssrc + (size_t)node * WD;
    int j = 0;
    for (; j + 8 <= c; j += 8) {
        int4 i0 = *(const int4*)(row + j);
        int4 i1 = *(const int4*)(row + j + 4);
        float4 v0 = ldrow<BF16IN, G>(hv, i0.x, g);
        float4 v1 = ldrow<BF16IN, G>(hv, i0.y, g);
        float4 v2 = ldrow<BF16IN, G>(hv, i0.z, g);
        float4 v3 = ldrow<BF16IN, G>(hv, i0.w, g);
        float4 v4 = ldrow<BF16IN, G>(hv, i1.x, g);
        float4 v5 = ldrow<BF16IN, G>(hv, i1.y, g);
        float4 v6 = ldrow<BF16IN, G>(hv, i1.z, g);
        float4 v7 = ldrow<BF16IN, G>(hv, i1.w, g);
        acc.x += ((v0.x + v1.x) + (v2.x + v3.x)) + ((v4.x + v5.x) + (v6.x + v7.x));
        acc.y += ((v0.y + v1.y) + (v2.y + v3.y)) + ((v4.y + v5.y) + (v6.y + v7.y));
        acc.z += ((v0.z + v1.z) + (v2.z + v3.z)) + ((v4.z + v5.z) + (v6.z + v7.z));
        acc.w += ((v0.w + v1.w) + (v2.w + v3.w)) + ((v4.w + v5.w) + (v6.w + v7.w));
    }
    for (; j + 4 <= c; j += 4) {
        int4 i0 = *(const int4*)(row + j);
        float4 v0 = ldrow<BF16IN, G>(hv, i0.x, g);
        float4 v1 = ldrow<BF16IN, G>(hv, i0.y, g);
        float4 v2 = ldrow<BF16IN, G>(hv, i0.z, g);
        float4 v3 = ldrow<BF16IN, G>(hv, i0.w, g);
        acc.x += (v0.x + v1.x) + (v2.x + v3.x);
        acc.y += (v0.y + v1.y) + (v2.y + v3.y);
        acc.z += (v0.z + v1.z) + (v2.z + v3.z);
        acc.w += (v0.w + v1.w) + (v2.w + v3.w);
    }
    for (; j < c; ++j) {
        float4 v = ldrow<BF16IN, G>(hv, row[j], g);
        acc.x += v.x; acc.y += v.y; acc.z += v.z; acc.w += v.w;
    }
    float4 bb = ((const float4*)b)[g];
    float4 o;
    o.x = fmaf(dd, acc.x, bb.x);
    o.y = fmaf(dd, acc.y, bb.y);
    o.z = fmaf(dd, acc.z, bb.z);
    o.w = fmaf(dd, acc.w, bb.w);
    ((float4*)(out + (size_t)node * F))[g] = o;
}

// ---------------- pooled mean over sorted batch ----------------
__device__ __forceinline__ int lower_bound_i(const int* __restrict__ a, int n, int key) {
    int lo = 0, hi = n;
    while (lo < hi) { int mid = (lo + hi) >> 1; if (a[mid] < key) lo = mid + 1; else hi = mid; }
    return lo;
}

__global__ void k_pool(const float* __restrict__ h, const int* __restrict__ batch,
                       float* __restrict__ out, int n) {
    int g = blockIdx.x;
    int start = lower_bound_i(batch, n, g);
    int end   = lower_bound_i(batch, n, g + 1);
    int tid = threadIdx.x;
    int f   = tid % F3;
    int sub = tid / F3;
    float acc = 0.f;
    for (int i = start + sub; i < end; i += 8)
        acc += h[(size_t)i * F3 + f];
    __shared__ float red[256];
    red[tid] = acc;
    __syncthreads();
    if (tid < F3) {
        float s2 = 0.f;
        for (int j = 0; j < 8; ++j) s2 += red[j * F3 + tid];
        float cnt = (float)(end - start);
        out[g * F3 + tid] = (end > start) ? s2 / cnt : 0.f;
    }
}

extern "C" void kernel_launch(void* const* d_in, const int* in_sizes, int n_in,
                              void* d_out, int out_size, void* d_ws, size_t ws_size,
                              hipStream_t stream) {
    const float* x  = (const float*)d_in[0];
    const int*   ei = (const int*)d_in[1];      // (2, E): first E = src, next E = dst
    const int*   batch = (const int*)d_in[2];
    const float* W1 = (const float*)d_in[3];
    const float* b1 = (const float*)d_in[4];
    const float* W2 = (const float*)d_in[5];
    const float* b2 = (const float*)d_in[6];
    const float* W3 = (const float*)d_in[7];
    const float* b3 = (const float*)d_in[8];
    float* out = (float*)d_out;

    const int n = in_sizes[0] / F0;     // 100000
    const int e = in_sizes[1] / 2;      // 3200000
    const int* src = ei;
    const int* dst = ei + e;

    // workspace (4-byte words), same 84.1 MB footprint as round 12:
    // cnt[NPAD] | dinv[NPAD] | ssrc[NPAD*WD] (+tail: bhist/binoff/cursor) | bufA[NN*64] | bufB[NN*64]
    // bufA life: pairs(int, 12.8MB) -> h1' bf16 -> h2' bf16 -> h3' f32
    int*   cnt    = (int*)d_ws;                        // NPAD
    float* dinv   = (float*)(cnt + NPAD);              // NPAD
    int*   ssrc   = (int*)(dinv + NPAD);               // NPAD*WD
    int*   bhist  = ssrc + (size_t)NN * WD;            // NBINS      (ssrc tail)
    int*   binoff = bhist + NBINS;                     // NBINS+1    (ssrc tail)
    int*   cursor = binoff + NBINS + 1;                // NBINS      (ssrc tail)
    float* bufA   = (float*)(ssrc + (size_t)NPAD * WD);// NN*64 words
    float* bufB   = bufA + (size_t)NN * 64;            // NN*64 words
    int*             pairs = (int*)bufA;               // alias
    __hip_bfloat16*  hbfA  = (__hip_bfloat16*)bufA;    // alias

    const int B = 256;

    // ---- binned ELL adjacency build (block-local counting sort, packed pairs) ----
    (void)hipMemsetAsync(bhist, 0, NBINS * sizeof(int), stream);
    k_hist<<<256, B, 0, stream>>>(dst, bhist, e);
    k_scan<<<1, 512, 0, stream>>>(bhist, binoff, cursor);
    k_part2<<<(e + CHUNK - 1) / CHUNK, B, 0, stream>>>(src, dst, cursor, pairs, e);
    k_place<<<NBINS, B, 0, stream>>>(pairs, binoff, ssrc, cnt, dinv);

    // ---- layer 1: h1' bf16 = (x@W1)*dinv ; gather -> bufB f32 ----
    k_gemm<F0, F1, false, true><<<(n + 63) / 64, B, 0, stream>>>(x, W1, dinv, hbfA, n);
    k_gather<F1, true><<<((size_t)n * (F1 / 4) + B - 1) / B, B, 0, stream>>>(cnt, ssrc, dinv, hbfA, b1, bufB, n);

    // ---- layer 2 ----
    k_gemm<F1, F2, true, true><<<(n + 63) / 64, B, 0, stream>>>(bufB, W2, dinv, hbfA, n);
    k_gather<F2, true><<<((size_t)n * (F2 / 4) + B - 1) / B, B, 0, stream>>>(cnt, ssrc, dinv, hbfA, b2, bufB, n);

    // ---- layer 3 (f32 h3') ----
    k_gemm<F2, F3, true, false><<<(n + 127) / 128, B, 0, stream>>>(bufB, W3, dinv, bufA, n);
    k_gather<F3, false><<<((size_t)n * (F3 / 4) + B - 1) / B, B, 0, stream>>>(cnt, ssrc, dinv, bufA, b3, bufB, n);

    // ---- pooled mean ----
    k_pool<<<NG, B, 0, stream>>>(bufB, batch, out, n);
}